// Round 1
// baseline (434.417 us; speedup 1.0000x reference)
//
#include <hip/hip_runtime.h>

#define NN 500
#define BB 32
#define TT 12
#define EMB 10

// ---------------- K1: S = softmax(relu(E E^T) with diag=stay), rows ----------------
__global__ __launch_bounds__(256) void k_softmaxS(const float* __restrict__ E,
                                                  const int* __restrict__ stay,
                                                  float* __restrict__ S) {
    const int i = blockIdx.x;
    const int tid = threadIdx.x;
    __shared__ float row[NN];
    __shared__ float red[256];
    float ei[EMB];
#pragma unroll
    for (int d = 0; d < EMB; ++d) ei[d] = E[i * EMB + d];
    const float stayf = (float)stay[0];

    float lmax = -1e30f;
    for (int j = tid; j < NN; j += 256) {
        float acc = 0.f;
#pragma unroll
        for (int d = 0; d < EMB; ++d) acc += ei[d] * E[j * EMB + d];
        float v = acc > 0.f ? acc : 0.f;
        if (j == i) v = stayf;
        row[j] = v;
        lmax = fmaxf(lmax, v);
    }
    red[tid] = lmax;
    __syncthreads();
    for (int s = 128; s > 0; s >>= 1) {
        if (tid < s) red[tid] = fmaxf(red[tid], red[tid + s]);
        __syncthreads();
    }
    const float rmax = red[0];
    __syncthreads();

    float lsum = 0.f;
    for (int j = tid; j < NN; j += 256) {
        float e = __expf(row[j] - rmax);
        row[j] = e;
        lsum += e;
    }
    red[tid] = lsum;
    __syncthreads();
    for (int s = 128; s > 0; s >>= 1) {
        if (tid < s) red[tid] += red[tid + s];
        __syncthreads();
    }
    const float inv = 1.0f / red[0];
    for (int j = tid; j < NN; j += 256) S[i * NN + j] = row[j] * inv;
}

// ---------------- K2/K3: y[b,n] = sum_m S[n,m] * xin[b,m] (wave per row) ----------------
__global__ __launch_bounds__(256) void k_matvecS(const float* __restrict__ S,
                                                 const float* __restrict__ xin,
                                                 float* __restrict__ yout) {
    const int b = blockIdx.y;
    const int w = threadIdx.x >> 6;
    const int lane = threadIdx.x & 63;
    const int n = blockIdx.x * 4 + w;
    const float* xb = xin + b * NN;
    const float* Sr = S + n * NN;
    float acc = 0.f;
    for (int m = lane; m < NN; m += 64) acc += Sr[m] * xb[m];
#pragma unroll
    for (int off = 32; off > 0; off >>= 1) acc += __shfl_down(acc, off, 64);
    if (lane == 0) yout[b * NN + n] = acc;
}

// ---------------- K4: per-node small weights from embeddings ----------------
__global__ __launch_bounds__(256) void k_smallpre(const float* __restrict__ E,
                                                  const float* __restrict__ wp,
                                                  const float* __restrict__ bp,
                                                  const float* __restrict__ wwsp,
                                                  const float* __restrict__ wwtp,
                                                  float* __restrict__ W,
                                                  float* __restrict__ biasN,
                                                  float* __restrict__ wws,
                                                  float* __restrict__ wwt) {
    const int n = blockIdx.x;
    const int tid = threadIdx.x;
    __shared__ float e[EMB];
    if (tid < EMB) e[tid] = E[n * EMB + tid];
    __syncthreads();
    if (tid < 144) {  // W[n, k, o]: k*48+o = tid ; wp index d*144 + tid
        float acc = 0.f;
#pragma unroll
        for (int d = 0; d < EMB; ++d) acc += e[d] * wp[d * 144 + tid];
        W[n * 144 + tid] = acc;
    } else if (tid < 208) {
        const int o = tid - 144;
        float acc = 0.f;
#pragma unroll
        for (int d = 0; d < EMB; ++d) acc += e[d] * bp[d * 64 + o];
        biasN[n * 64 + o] = acc;
    } else if (tid < 216) {
        const int o = tid - 208;
        float acc = 0.f;
#pragma unroll
        for (int d = 0; d < EMB; ++d) acc += e[d] * wwsp[d * 8 + o];
        wws[n * 8 + o] = acc;
    } else if (tid < 224) {
        const int o = tid - 216;
        float acc = 0.f;
#pragma unroll
        for (int d = 0; d < EMB; ++d) acc += e[d] * wwtp[d * 8 + o];
        wwt[n * 8 + o] = acc;
    }
}

// ---------------- K5: M[b,n] = mean_f xws, wsum[b,n] = sum_t xw[b,t,n]*T[t] ----------------
__global__ __launch_bounds__(128) void k_Mwsum(const float* __restrict__ xwin,
                                               const float* __restrict__ S,
                                               const int* __restrict__ bidx,
                                               const int* __restrict__ jumpc,
                                               const float* __restrict__ Tp,
                                               float* __restrict__ M,
                                               float* __restrict__ wsum) {
    const int b = blockIdx.y;
    const int n0 = blockIdx.x * 125;
    const int tid = threadIdx.x;
    __shared__ float xsf[NN];
    __shared__ float Tl[TT];
    const int t0 = bidx[0], t1 = bidx[1], t2 = bidx[2];
    if (tid < TT) Tl[tid] = Tp[tid];
    const float* xb = xwin + (size_t)b * TT * NN;
    for (int m = tid; m < NN; m += 128)
        xsf[m] = xb[t0 * NN + m] + xb[t1 * NN + m] + xb[t2 * NN + m];
    __syncthreads();
    if (tid < 125) {
        const int n = n0 + tid;
        float ws_ = 0.f;
#pragma unroll
        for (int t = 0; t < TT; ++t) ws_ += xb[t * NN + n] * Tl[t];
        const float jc = (float)jumpc[0];
        const float jterm = jc * (2.f * xb[t0 * NN + n] + xb[t1 * NN + n]);
        float acc = 0.f;
        for (int m = 0; m < NN; ++m) acc += xsf[m] * S[m * NN + n];
        M[b * NN + n] = (acc + jterm) * (1.f / 3.f);
        wsum[b * NN + n] = ws_;
    }
}

// ---------------- K6: fused dual conv + relu + partial mean/max reduce ----------------
__global__ __launch_bounds__(256) void k_conv(const float* __restrict__ MPG,
                                              const float* __restrict__ wm,
                                              const float* __restrict__ bmv,
                                              const float* __restrict__ wx,
                                              const float* __restrict__ bxv,
                                              float* __restrict__ partials) {
    const int b = blockIdx.y;
    const int tid = threadIdx.x;
    const int ry = tid >> 7;
    const int tx = tid & 127;
    const int r = blockIdx.x * 2 + ry;
    const int c0 = tx * 4;
    const bool active = (c0 < NN);

    float acc[8][4];
#pragma unroll
    for (int c = 0; c < 4; ++c) {
        const float bbm = bmv[c];
        const float bbx = bxv[c];
#pragma unroll
        for (int v = 0; v < 4; ++v) {
            acc[c][v] = bbm;
            acc[c + 4][v] = bbx;
        }
    }

    const float* base_b = MPG + (size_t)b * (TT * NN * NN);
    for (int t = 0; t < TT; ++t) {
#pragma unroll
        for (int kh = 0; kh < 3; ++kh) {
            const int row = r + kh - 1;
            const bool rowok = (row >= 0) && (row < NN);
            const float* rp = base_b + (ptrdiff_t)(t * NN + row) * NN;
            float in[6];
#pragma unroll
            for (int u = 0; u < 6; ++u) {
                const int col = c0 - 1 + u;
                const bool ok = rowok && (col >= 0) && (col < NN);
                in[u] = ok ? rp[col] : 0.0f;
            }
#pragma unroll
            for (int c = 0; c < 4; ++c) {
#pragma unroll
                for (int kw = 0; kw < 3; ++kw) {
                    const int wi = ((c * TT + t) * 3 + kh) * 3 + kw;
                    const float w1 = wm[wi];
                    const float w2 = wx[wi];
#pragma unroll
                    for (int v = 0; v < 4; ++v) {
                        acc[c][v] = fmaf(in[v + kw], w1, acc[c][v]);
                        acc[c + 4][v] = fmaf(in[v + kw], w2, acc[c + 4][v]);
                    }
                }
            }
        }
    }

    float vals[8];
#pragma unroll
    for (int c = 0; c < 8; ++c) vals[c] = 0.f;
    if (active) {
#pragma unroll
        for (int c = 0; c < 4; ++c) {
            float s0 = 0.f;
#pragma unroll
            for (int v = 0; v < 4; ++v) s0 += fmaxf(acc[c][v], 0.f);
            vals[c] = s0;
            float m0 = 0.f;
#pragma unroll
            for (int v = 0; v < 4; ++v) m0 = fmaxf(m0, fmaxf(acc[c + 4][v], 0.f));
            vals[c + 4] = m0;
        }
    }

    __shared__ float red8[256 * 8];
#pragma unroll
    for (int c = 0; c < 8; ++c) red8[tid * 8 + c] = vals[c];
    __syncthreads();
    for (int s = 128; s > 0; s >>= 1) {
        if (tid < s) {
#pragma unroll
            for (int c = 0; c < 4; ++c) red8[tid * 8 + c] += red8[(tid + s) * 8 + c];
#pragma unroll
            for (int c = 4; c < 8; ++c) red8[tid * 8 + c] = fmaxf(red8[tid * 8 + c], red8[(tid + s) * 8 + c]);
        }
        __syncthreads();
    }
    if (tid < 8) partials[((size_t)b * 250 + blockIdx.x) * 8 + tid] = red8[tid];
}

// ---------------- K7: reduce partials -> topo[b][8] ----------------
__global__ __launch_bounds__(256) void k_topo(const float* __restrict__ partials,
                                              float* __restrict__ topo) {
    const int b = blockIdx.x;
    const int tid = threadIdx.x;
    const int c = tid & 7;
    const int g = tid >> 3;  // 32 groups
    float vs = 0.f, vm = 0.f;
    for (int rp = g; rp < 250; rp += 32) {
        const float v = partials[((size_t)b * 250 + rp) * 8 + c];
        vs += v;
        vm = fmaxf(vm, v);
    }
    __shared__ float red[256];
    red[tid] = (c < 4) ? vs : vm;
    __syncthreads();
    for (int s = 16; s > 0; s >>= 1) {
        if (g < s) {
            const float a = red[tid];
            const float bv = red[tid + s * 8];
            red[tid] = (c < 4) ? (a + bv) : fmaxf(a, bv);
        }
        __syncthreads();
    }
    if (tid < 8) topo[b * 8 + tid] = (tid < 4) ? red[tid] * (1.f / (NN * (float)NN)) : red[tid];
}

// ---------------- K8: assemble output ----------------
__global__ __launch_bounds__(64) void k_out(const float* __restrict__ x,
                                            const float* __restrict__ y1,
                                            const float* __restrict__ y2,
                                            const float* __restrict__ W,
                                            const float* __restrict__ biasN,
                                            const float* __restrict__ wws,
                                            const float* __restrict__ wwt,
                                            const float* __restrict__ M,
                                            const float* __restrict__ wsum,
                                            const float* __restrict__ topo,
                                            float* __restrict__ out) {
    const int bn = blockIdx.x;
    const int b = bn / NN;
    const int n = bn - b * NN;
    const int o = threadIdx.x;
    float val;
    if (o < 48) {
        val = x[bn] * W[n * 144 + o] + y1[bn] * W[n * 144 + 48 + o] + y2[bn] * W[n * 144 + 96 + o];
    } else if (o < 56) {
        const int oo = o - 48;
        val = M[bn] * wws[n * 8 + oo] * topo[b * 8 + oo];
    } else {
        const int oo = o - 56;
        val = wsum[bn] * wwt[n * 8 + oo];
    }
    out[(size_t)bn * 64 + o] = val + biasN[n * 64 + o];
}

extern "C" void kernel_launch(void* const* d_in, const int* in_sizes, int n_in,
                              void* d_out, int out_size, void* d_ws, size_t ws_size,
                              hipStream_t stream) {
    const float* x    = (const float*)d_in[0];
    const float* xw   = (const float*)d_in[1];
    const float* E    = (const float*)d_in[2];
    const float* MPG  = (const float*)d_in[4];
    const int*   bidx = (const int*)d_in[5];
    const int*   stay = (const int*)d_in[7];
    const int*   jump = (const int*)d_in[8];
    const float* wp   = (const float*)d_in[9];
    const float* wwsp = (const float*)d_in[10];
    const float* wwtp = (const float*)d_in[11];
    const float* bp   = (const float*)d_in[12];
    const float* Tp   = (const float*)d_in[13];
    const float* cmw  = (const float*)d_in[14];
    const float* cmb  = (const float*)d_in[15];
    const float* cxw  = (const float*)d_in[16];
    const float* cxb  = (const float*)d_in[17];
    float* out = (float*)d_out;

    float* w = (float*)d_ws;
    float* S     = w;               // 250000
    float* y1    = S + 250000;      // 16000
    float* y2    = y1 + 16000;      // 16000
    float* W     = y2 + 16000;      // 72000
    float* biasN = W + 72000;       // 32000
    float* wws   = biasN + 32000;   // 4000
    float* wwt   = wws + 4000;      // 4000
    float* M     = wwt + 4000;      // 16000
    float* wsum  = M + 16000;       // 16000
    float* parts = wsum + 16000;    // 64000
    float* topo  = parts + 64000;   // 256

    k_softmaxS<<<NN, 256, 0, stream>>>(E, stay, S);
    k_matvecS<<<dim3(125, BB), 256, 0, stream>>>(S, x, y1);
    k_matvecS<<<dim3(125, BB), 256, 0, stream>>>(S, y1, y2);
    k_smallpre<<<NN, 256, 0, stream>>>(E, wp, bp, wwsp, wwtp, W, biasN, wws, wwt);
    k_Mwsum<<<dim3(4, BB), 128, 0, stream>>>(xw, S, bidx, jump, Tp, M, wsum);
    k_conv<<<dim3(250, BB), 256, 0, stream>>>(MPG, cmw, cmb, cxw, cxb, parts);
    k_topo<<<BB, 256, 0, stream>>>(parts, topo);
    k_out<<<BB * NN, 64, 0, stream>>>(x, y1, y2, W, biasN, wws, wwt, M, wsum, topo, out);
}

// Round 2
// 246.942 us; speedup vs baseline: 1.7592x; 1.7592x over previous
//
#include <hip/hip_runtime.h>

#define NN 500
#define BB 32
#define TT 12
#define EMB 10

// ---------------- K1: S = softmax(relu(E E^T) with diag=stay), rows ----------------
__global__ __launch_bounds__(256) void k_softmaxS(const float* __restrict__ E,
                                                  const int* __restrict__ stay,
                                                  float* __restrict__ S) {
    const int i = blockIdx.x;
    const int tid = threadIdx.x;
    __shared__ float row[NN];
    __shared__ float red[256];
    float ei[EMB];
#pragma unroll
    for (int d = 0; d < EMB; ++d) ei[d] = E[i * EMB + d];
    const float stayf = (float)stay[0];

    float lmax = -1e30f;
    for (int j = tid; j < NN; j += 256) {
        float acc = 0.f;
#pragma unroll
        for (int d = 0; d < EMB; ++d) acc += ei[d] * E[j * EMB + d];
        float v = acc > 0.f ? acc : 0.f;
        if (j == i) v = stayf;
        row[j] = v;
        lmax = fmaxf(lmax, v);
    }
    red[tid] = lmax;
    __syncthreads();
    for (int s = 128; s > 0; s >>= 1) {
        if (tid < s) red[tid] = fmaxf(red[tid], red[tid + s]);
        __syncthreads();
    }
    const float rmax = red[0];
    __syncthreads();

    float lsum = 0.f;
    for (int j = tid; j < NN; j += 256) {
        float e = __expf(row[j] - rmax);
        row[j] = e;
        lsum += e;
    }
    red[tid] = lsum;
    __syncthreads();
    for (int s = 128; s > 0; s >>= 1) {
        if (tid < s) red[tid] += red[tid + s];
        __syncthreads();
    }
    const float inv = 1.0f / red[0];
    for (int j = tid; j < NN; j += 256) S[i * NN + j] = row[j] * inv;
}

// ---------------- K2/K3: y[b,n] = sum_m S[n,m] * xin[b,m] (wave per row) ----------------
__global__ __launch_bounds__(256) void k_matvecS(const float* __restrict__ S,
                                                 const float* __restrict__ xin,
                                                 float* __restrict__ yout) {
    const int b = blockIdx.y;
    const int w = threadIdx.x >> 6;
    const int lane = threadIdx.x & 63;
    const int n = blockIdx.x * 4 + w;
    const float* xb = xin + b * NN;
    const float* Sr = S + n * NN;
    float acc = 0.f;
    for (int m = lane; m < NN; m += 64) acc += Sr[m] * xb[m];
#pragma unroll
    for (int off = 32; off > 0; off >>= 1) acc += __shfl_down(acc, off, 64);
    if (lane == 0) yout[b * NN + n] = acc;
}

// ---------------- K4: per-node small weights from embeddings ----------------
__global__ __launch_bounds__(256) void k_smallpre(const float* __restrict__ E,
                                                  const float* __restrict__ wp,
                                                  const float* __restrict__ bp,
                                                  const float* __restrict__ wwsp,
                                                  const float* __restrict__ wwtp,
                                                  float* __restrict__ W,
                                                  float* __restrict__ biasN,
                                                  float* __restrict__ wws,
                                                  float* __restrict__ wwt) {
    const int n = blockIdx.x;
    const int tid = threadIdx.x;
    __shared__ float e[EMB];
    if (tid < EMB) e[tid] = E[n * EMB + tid];
    __syncthreads();
    if (tid < 144) {
        float acc = 0.f;
#pragma unroll
        for (int d = 0; d < EMB; ++d) acc += e[d] * wp[d * 144 + tid];
        W[n * 144 + tid] = acc;
    } else if (tid < 208) {
        const int o = tid - 144;
        float acc = 0.f;
#pragma unroll
        for (int d = 0; d < EMB; ++d) acc += e[d] * bp[d * 64 + o];
        biasN[n * 64 + o] = acc;
    } else if (tid < 216) {
        const int o = tid - 208;
        float acc = 0.f;
#pragma unroll
        for (int d = 0; d < EMB; ++d) acc += e[d] * wwsp[d * 8 + o];
        wws[n * 8 + o] = acc;
    } else if (tid < 224) {
        const int o = tid - 216;
        float acc = 0.f;
#pragma unroll
        for (int d = 0; d < EMB; ++d) acc += e[d] * wwtp[d * 8 + o];
        wwt[n * 8 + o] = acc;
    }
}

// ---------------- K5: M[b,n] = mean_f xws, wsum[b,n] = sum_t xw[b,t,n]*T[t] ----------------
__global__ __launch_bounds__(128) void k_Mwsum(const float* __restrict__ xwin,
                                               const float* __restrict__ S,
                                               const int* __restrict__ bidx,
                                               const int* __restrict__ jumpc,
                                               const float* __restrict__ Tp,
                                               float* __restrict__ M,
                                               float* __restrict__ wsum) {
    const int b = blockIdx.y;
    const int n0 = blockIdx.x * 125;
    const int tid = threadIdx.x;
    __shared__ float xsf[NN];
    __shared__ float Tl[TT];
    const int t0 = bidx[0], t1 = bidx[1], t2 = bidx[2];
    if (tid < TT) Tl[tid] = Tp[tid];
    const float* xb = xwin + (size_t)b * TT * NN;
    for (int m = tid; m < NN; m += 128)
        xsf[m] = xb[t0 * NN + m] + xb[t1 * NN + m] + xb[t2 * NN + m];
    __syncthreads();
    if (tid < 125) {
        const int n = n0 + tid;
        float ws_ = 0.f;
#pragma unroll
        for (int t = 0; t < TT; ++t) ws_ += xb[t * NN + n] * Tl[t];
        const float jc = (float)jumpc[0];
        const float jterm = jc * (2.f * xb[t0 * NN + n] + xb[t1 * NN + n]);
        float acc = 0.f;
        for (int m = 0; m < NN; ++m) acc += xsf[m] * S[m * NN + n];
        M[b * NN + n] = (acc + jterm) * (1.f / 3.f);
        wsum[b * NN + n] = ws_;
    }
}

// ---------------- K6: fused dual conv + relu + partial mean/max reduce (LDS double-buffered) ----------------
__global__ __launch_bounds__(256) void k_conv(const float* __restrict__ MPG,
                                              const float* __restrict__ wm,
                                              const float* __restrict__ bmv,
                                              const float* __restrict__ wx,
                                              const float* __restrict__ bxv,
                                              float* __restrict__ partials) {
    const int b = blockIdx.y;
    const int r0 = blockIdx.x * 2;   // output rows r0, r0+1
    const int tid = threadIdx.x;
    const int ry = tid >> 7;         // 0..1
    const int tx = tid & 127;
    const int c0 = tx * 4;
    const bool active = (c0 < NN);
    const bool left_ok = (c0 > 0);
    const bool right_ok = (c0 + 4 < NN);

    __shared__ float buf[2][4][512];   // dbuf x 4 staged rows x padded width
    __shared__ float wred[4][8];

    const float* base_b = MPG + (size_t)b * (TT * NN * NN);

    // staging mapping: float4 idx f = tid and tid+256; row = f/125, col4 = f%125
    const int f41 = tid + 256;
    const int s_row0 = tid / 125;
    const int s_col0 = (tid - s_row0 * 125) * 4;
    const int s_row1 = f41 / 125;
    const int s_col1 = (f41 - s_row1 * 125) * 4;
    const bool s1ok = f41 < 500;
    const int gr0 = r0 - 1 + s_row0;
    const int gr1 = r0 - 1 + s_row1;
    const bool g0ok = (gr0 >= 0) && (gr0 < NN);
    const bool g1ok = s1ok && (gr1 >= 0) && (gr1 < NN);

    float acc[8][4];
#pragma unroll
    for (int c = 0; c < 4; ++c) {
        const float bbm = bmv[c];
        const float bbx = bxv[c];
#pragma unroll
        for (int v = 0; v < 4; ++v) {
            acc[c][v] = bbm;
            acc[c + 4][v] = bbx;
        }
    }

    float4 p0, p1;
    // prologue: stage t=0
    p0 = make_float4(0.f, 0.f, 0.f, 0.f);
    p1 = make_float4(0.f, 0.f, 0.f, 0.f);
    if (g0ok) p0 = *reinterpret_cast<const float4*>(base_b + ((size_t)0 * NN + gr0) * NN + s_col0);
    if (g1ok) p1 = *reinterpret_cast<const float4*>(base_b + ((size_t)0 * NN + gr1) * NN + s_col1);
    *reinterpret_cast<float4*>(&buf[0][s_row0][s_col0]) = p0;
    if (s1ok) *reinterpret_cast<float4*>(&buf[0][s_row1][s_col1]) = p1;
    __syncthreads();

    for (int t = 0; t < TT; ++t) {
        const int pb = t & 1;
        const bool pf = (t + 1) < TT;
        // issue next-tile global loads early (hidden under compute)
        if (pf) {
            p0 = make_float4(0.f, 0.f, 0.f, 0.f);
            p1 = make_float4(0.f, 0.f, 0.f, 0.f);
            if (g0ok) p0 = *reinterpret_cast<const float4*>(base_b + ((size_t)(t + 1) * NN + gr0) * NN + s_col0);
            if (g1ok) p1 = *reinterpret_cast<const float4*>(base_b + ((size_t)(t + 1) * NN + gr1) * NN + s_col1);
        }

        // compute from buf[pb]
#pragma unroll
        for (int kh = 0; kh < 3; ++kh) {
            const float* lr = &buf[pb][ry + kh][0];
            const float4 v = *reinterpret_cast<const float4*>(&lr[c0]);
            const float lf = left_ok ? lr[c0 - 1] : 0.f;
            const float rt = right_ok ? lr[c0 + 4] : 0.f;
            const float in[6] = {lf, v.x, v.y, v.z, v.w, rt};
#pragma unroll
            for (int c = 0; c < 4; ++c) {
                const float* wmc = wm + (c * TT + t) * 9 + kh * 3;
                const float* wxc = wx + (c * TT + t) * 9 + kh * 3;
#pragma unroll
                for (int kw = 0; kw < 3; ++kw) {
                    const float w1 = wmc[kw];
                    const float w2 = wxc[kw];
#pragma unroll
                    for (int vv = 0; vv < 4; ++vv) {
                        acc[c][vv] = fmaf(in[vv + kw], w1, acc[c][vv]);
                        acc[c + 4][vv] = fmaf(in[vv + kw], w2, acc[c + 4][vv]);
                    }
                }
            }
        }

        // write next tile into the other buffer, then single barrier
        if (pf) {
            *reinterpret_cast<float4*>(&buf[pb ^ 1][s_row0][s_col0]) = p0;
            if (s1ok) *reinterpret_cast<float4*>(&buf[pb ^ 1][s_row1][s_col1]) = p1;
        }
        __syncthreads();
    }

    // relu + per-thread reduce
    float vals[8];
#pragma unroll
    for (int c = 0; c < 8; ++c) vals[c] = 0.f;
    if (active) {
#pragma unroll
        for (int c = 0; c < 4; ++c) {
            float s0 = 0.f;
#pragma unroll
            for (int v = 0; v < 4; ++v) s0 += fmaxf(acc[c][v], 0.f);
            vals[c] = s0;
            float m0 = 0.f;
#pragma unroll
            for (int v = 0; v < 4; ++v) m0 = fmaxf(m0, fmaxf(acc[c + 4][v], 0.f));
            vals[c + 4] = m0;
        }
    }

    // wave butterfly reduce
#pragma unroll
    for (int off = 32; off > 0; off >>= 1) {
#pragma unroll
        for (int c = 0; c < 4; ++c) vals[c] += __shfl_xor(vals[c], off, 64);
#pragma unroll
        for (int c = 4; c < 8; ++c) vals[c] = fmaxf(vals[c], __shfl_xor(vals[c], off, 64));
    }
    const int wv = tid >> 6;
    const int lane = tid & 63;
    if (lane == 0) {
#pragma unroll
        for (int c = 0; c < 8; ++c) wred[wv][c] = vals[c];
    }
    __syncthreads();
    if (tid < 8) {
        const float a0 = wred[0][tid], a1 = wred[1][tid], a2 = wred[2][tid], a3 = wred[3][tid];
        const float r = (tid < 4) ? (a0 + a1 + a2 + a3) : fmaxf(fmaxf(a0, a1), fmaxf(a2, a3));
        partials[((size_t)b * 250 + blockIdx.x) * 8 + tid] = r;
    }
}

// ---------------- K7: reduce partials -> topo[b][8] ----------------
__global__ __launch_bounds__(256) void k_topo(const float* __restrict__ partials,
                                              float* __restrict__ topo) {
    const int b = blockIdx.x;
    const int tid = threadIdx.x;
    const int c = tid & 7;
    const int g = tid >> 3;  // 32 groups
    float vs = 0.f, vm = 0.f;
    for (int rp = g; rp < 250; rp += 32) {
        const float v = partials[((size_t)b * 250 + rp) * 8 + c];
        vs += v;
        vm = fmaxf(vm, v);
    }
    __shared__ float red[256];
    red[tid] = (c < 4) ? vs : vm;
    __syncthreads();
    for (int s = 16; s > 0; s >>= 1) {
        if (g < s) {
            const float a = red[tid];
            const float bv = red[tid + s * 8];
            red[tid] = (c < 4) ? (a + bv) : fmaxf(a, bv);
        }
        __syncthreads();
    }
    if (tid < 8) topo[b * 8 + tid] = (tid < 4) ? red[tid] * (1.f / (NN * (float)NN)) : red[tid];
}

// ---------------- K8: assemble output ----------------
__global__ __launch_bounds__(64) void k_out(const float* __restrict__ x,
                                            const float* __restrict__ y1,
                                            const float* __restrict__ y2,
                                            const float* __restrict__ W,
                                            const float* __restrict__ biasN,
                                            const float* __restrict__ wws,
                                            const float* __restrict__ wwt,
                                            const float* __restrict__ M,
                                            const float* __restrict__ wsum,
                                            const float* __restrict__ topo,
                                            float* __restrict__ out) {
    const int bn = blockIdx.x;
    const int b = bn / NN;
    const int n = bn - b * NN;
    const int o = threadIdx.x;
    float val;
    if (o < 48) {
        val = x[bn] * W[n * 144 + o] + y1[bn] * W[n * 144 + 48 + o] + y2[bn] * W[n * 144 + 96 + o];
    } else if (o < 56) {
        const int oo = o - 48;
        val = M[bn] * wws[n * 8 + oo] * topo[b * 8 + oo];
    } else {
        const int oo = o - 56;
        val = wsum[bn] * wwt[n * 8 + oo];
    }
    out[(size_t)bn * 64 + o] = val + biasN[n * 64 + o];
}

extern "C" void kernel_launch(void* const* d_in, const int* in_sizes, int n_in,
                              void* d_out, int out_size, void* d_ws, size_t ws_size,
                              hipStream_t stream) {
    const float* x    = (const float*)d_in[0];
    const float* xw   = (const float*)d_in[1];
    const float* E    = (const float*)d_in[2];
    const float* MPG  = (const float*)d_in[4];
    const int*   bidx = (const int*)d_in[5];
    const int*   stay = (const int*)d_in[7];
    const int*   jump = (const int*)d_in[8];
    const float* wp   = (const float*)d_in[9];
    const float* wwsp = (const float*)d_in[10];
    const float* wwtp = (const float*)d_in[11];
    const float* bp   = (const float*)d_in[12];
    const float* Tp   = (const float*)d_in[13];
    const float* cmw  = (const float*)d_in[14];
    const float* cmb  = (const float*)d_in[15];
    const float* cxw  = (const float*)d_in[16];
    const float* cxb  = (const float*)d_in[17];
    float* out = (float*)d_out;

    float* w = (float*)d_ws;
    float* S     = w;               // 250000
    float* y1    = S + 250000;      // 16000
    float* y2    = y1 + 16000;      // 16000
    float* W     = y2 + 16000;      // 72000
    float* biasN = W + 72000;       // 32000
    float* wws   = biasN + 32000;   // 4000
    float* wwt   = wws + 4000;      // 4000
    float* M     = wwt + 4000;      // 16000
    float* wsum  = M + 16000;       // 16000
    float* parts = wsum + 16000;    // 64000
    float* topo  = parts + 64000;   // 256

    k_softmaxS<<<NN, 256, 0, stream>>>(E, stay, S);
    k_matvecS<<<dim3(125, BB), 256, 0, stream>>>(S, x, y1);
    k_matvecS<<<dim3(125, BB), 256, 0, stream>>>(S, y1, y2);
    k_smallpre<<<NN, 256, 0, stream>>>(E, wp, bp, wwsp, wwtp, W, biasN, wws, wwt);
    k_Mwsum<<<dim3(4, BB), 128, 0, stream>>>(xw, S, bidx, jump, Tp, M, wsum);
    k_conv<<<dim3(250, BB), 256, 0, stream>>>(MPG, cmw, cmb, cxw, cxb, parts);
    k_topo<<<BB, 256, 0, stream>>>(parts, topo);
    k_out<<<BB * NN, 64, 0, stream>>>(x, y1, y2, W, biasN, wws, wwt, M, wsum, topo, out);
}